// Round 1
// 723.795 us; speedup vs baseline: 1.2700x; 1.2700x over previous
//
#include <hip/hip_runtime.h>
#include <hip/hip_bf16.h>

typedef __hip_bfloat16 bf16;
typedef __attribute__((ext_vector_type(8))) short bfrag;   // 8 bf16 = 4 VGPRs
typedef __attribute__((ext_vector_type(4))) float ffrag;   // 4 fp32 acc

#define CDIM 128
#define TDIMC 64
#define MSGD 64

__device__ __forceinline__ unsigned short f2bf(float f) {
    union { __hip_bfloat16 h; unsigned short u; } cv;
    cv.h = __float2bfloat16(f);
    return cv.u;
}

// ---------------- edge_index dtype detection ----------------
__global__ void detect_kernel(const int* __restrict__ ei, int samp, int* __restrict__ flag) {
    int i = blockIdx.x * blockDim.x + threadIdx.x;
    if (i < samp) {
        if (ei[2 * i + 1] != 0) atomicOr(flag, 1);   // int32 data -> odd words are dst values
    }
}

// ---------------- dst histogram straight from ei ----------------
__global__ void hist_kernel(const int* __restrict__ ei, int E, const int* __restrict__ flag,
                            int* __restrict__ count) {
    int e = blockIdx.x * 256 + threadIdx.x;
    if (e >= E) return;
    int is32 = *flag;
    int d = is32 ? ei[E + e] : ei[2 * (E + e)];   // int64 path: low word
    atomicAdd(&count[d], 1);
}

// ---------------- exclusive scan over count[N] -> cur[N] ----------------
__global__ __launch_bounds__(1024)
void scan_kernel(const int* __restrict__ count, int N, int* __restrict__ cur) {
    __shared__ int wsum[16];
    __shared__ int woff[16];
    __shared__ int carry;
    int t = threadIdx.x;
    int lane = t & 63, wv = t >> 6;
    if (t == 0) carry = 0;
    __syncthreads();
    for (int base = 0; base < N; base += 1024) {
        int i = base + t;
        int v = (i < N) ? count[i] : 0;
        int incl = v;
#pragma unroll
        for (int off = 1; off < 64; off <<= 1) {
            int n = __shfl_up(incl, off, 64);
            if (lane >= off) incl += n;
        }
        if (lane == 63) wsum[wv] = incl;
        __syncthreads();
        if (wv == 0) {
            int ws = (lane < 16) ? wsum[lane] : 0;
            int wi = ws;
#pragma unroll
            for (int off = 1; off < 16; off <<= 1) {
                int n = __shfl_up(wi, off, 64);
                if (lane >= off) wi += n;
            }
            if (lane < 16) woff[lane] = wi - ws;   // exclusive wave offset
        }
        __syncthreads();
        int excl = carry + woff[wv] + incl - v;
        if (i < N) cur[i] = excl;
        __syncthreads();
        if (t == 1023) carry = excl + v;
        __syncthreads();
    }
}

// ---------------- scatter into dst-sorted order ----------------
// Also precomputes rel_t here (breaks the src_s -> last_update dependent-gather
// chain out of edge_kernel's header; this kernel is throughput-bound anyway).
__global__ void scatter_kernel(const int* __restrict__ ei, int E, const int* __restrict__ flag,
                               const int* __restrict__ tarr, const int* __restrict__ last_update,
                               int* __restrict__ cur,
                               int* __restrict__ perm, int* __restrict__ src_s,
                               int* __restrict__ dst_s, float* __restrict__ relt_s) {
    int e = blockIdx.x * 256 + threadIdx.x;
    if (e >= E) return;
    int is32 = *flag;
    int s = is32 ? ei[e] : ei[2 * e];
    int d = is32 ? ei[E + e] : ei[2 * (E + e)];
    int pos = atomicAdd(&cur[d], 1);
    perm[pos] = e;
    src_s[pos] = s;
    dst_s[pos] = d;
    relt_s[pos] = (float)(last_update[s] - tarr[e]);
}

// ---------------- weight pre-transpose + bf16 convert ----------------
__global__ void wconv_kernel(const float* __restrict__ Wq, const float* __restrict__ Wk,
                             const float* __restrict__ Wv, const float* __restrict__ Ws,
                             const float* __restrict__ We,
                             short* __restrict__ Wt, short* __restrict__ Wet) {
    int idx = blockIdx.x * 256 + threadIdx.x;
    if (idx >= 5 * 16384) return;
    int mat = idx >> 14;
    int r = idx & 16383;
    int n = r >> 7, kk = r & 127;
    const float* W = (mat == 0) ? Wq : (mat == 1) ? Wk : (mat == 2) ? Wv : (mat == 3) ? Ws : We;
    short bv = (short)f2bf(W[kk * 128 + n]);
    if (mat < 4) Wt[(size_t)mat * 16384 + n * 128 + kk] = bv;
    else         Wet[n * 128 + kk] = bv;
}

// ---------------- MFMA node projections: wave w -> {q,k,v,skip->out} ----------------
__global__ __launch_bounds__(256)
void proj_kernel(const float* __restrict__ x, const short* __restrict__ Wt,
                 const float* __restrict__ bq, const float* __restrict__ bk,
                 const float* __restrict__ bv, const float* __restrict__ bs,
                 float* __restrict__ q, float* __restrict__ k, float* __restrict__ v,
                 float* __restrict__ out, int N) {
    __shared__ __attribute__((aligned(16))) short sx[64][136];
    int tid = threadIdx.x;
    int n0 = blockIdx.x * 64;
    const float4* x4 = (const float4*)x;
    for (int i = tid; i < 64 * 32; i += 256) {
        int nl = i >> 5, c4 = i & 31;
        int n = n0 + nl;
        float4 f = (n < N) ? x4[(size_t)n * 32 + c4] : make_float4(0.f, 0.f, 0.f, 0.f);
        unsigned int lo = ((unsigned int)f2bf(f.y) << 16) | f2bf(f.x);
        unsigned int hi = ((unsigned int)f2bf(f.w) << 16) | f2bf(f.z);
        *(uint2*)&sx[nl][c4 * 4] = make_uint2(lo, hi);
    }
    __syncthreads();

    int lane = tid & 63, wv = tid >> 6;
    int n15 = lane & 15, quad = lane >> 4;
    const short* W = Wt + (size_t)wv * 16384;
    const float* bias = (wv == 0) ? bq : (wv == 1) ? bk : (wv == 2) ? bv : bs;
    float* dstp = (wv == 0) ? q : (wv == 1) ? k : (wv == 2) ? v : out;

    ffrag acc[4][8];
#pragma unroll
    for (int r = 0; r < 4; ++r)
#pragma unroll
        for (int c = 0; c < 8; ++c)
            acc[r][c] = (ffrag){0.f, 0.f, 0.f, 0.f};

#pragma unroll
    for (int kc = 0; kc < 4; ++kc) {
        int kk = kc * 32 + quad * 8;
        bfrag a[4];
#pragma unroll
        for (int r = 0; r < 4; ++r)
            a[r] = *(const bfrag*)&sx[r * 16 + n15][kk];
#pragma unroll
        for (int c = 0; c < 8; ++c) {
            bfrag b = *(const bfrag*)&W[(c * 16 + n15) * 128 + kk];
#pragma unroll
            for (int r = 0; r < 4; ++r)
                acc[r][c] = __builtin_amdgcn_mfma_f32_16x16x32_bf16(a[r], b, acc[r][c], 0, 0, 0);
        }
    }

#pragma unroll
    for (int c = 0; c < 8; ++c) {
        int col = c * 16 + n15;
        float bval = bias[col];
#pragma unroll
        for (int r = 0; r < 4; ++r) {
#pragma unroll
            for (int g = 0; g < 4; ++g) {
                int n = n0 + r * 16 + quad * 4 + g;
                if (n < N) dstp[(size_t)n * CDIM + col] = acc[r][c][g] + bval;
            }
        }
    }
}

// ---------------- MFMA edge kernel, FUSED with segment-softmax aggregation ----------------
// Block = 64 consecutive dst-sorted edges, 4 waves x 16 edges. Single bf16 LDS buffer:
// edge_attr staged, then e = edge_attr @ We overlaid. The overlay WRITE needs no barrier
// (transitively depends on all A-frag ds_reads via the MFMA chain); the phase-3 READ of e
// DOES need the barrier (SIMT race otherwise — earlier round's absmax=3.2 bug).
// Phase 3: per wave, iterate the 16 sorted edges in order, accumulate
// num += (v+e)*exp(alpha), den += exp(alpha) in registers, and flush with f32 atomics on
// dst change (~2.3 segments / wave at avg degree 12). This replaces the 154 MB ve2 store +
// 158 MB agg re-read with ~50 MB of atomics and kills the agg dispatch.
__global__ __launch_bounds__(256)
void edge_kernel(const int* __restrict__ src_s, const int* __restrict__ dst_s,
                 const float* __restrict__ relt_s, const int* __restrict__ perm,
                 const float* __restrict__ msg,
                 const float* __restrict__ time_w, const float* __restrict__ time_b,
                 const short* __restrict__ Wet,
                 const float* __restrict__ q, const float* __restrict__ k, const float* __restrict__ v,
                 float* __restrict__ num, float* __restrict__ den,
                 int E) {
    __shared__ __attribute__((aligned(16))) short sbuf[64][136];
    __shared__ int s_src[64], s_dst[64], s_perm[64];
    __shared__ float s_relt[64];
    int tid = threadIdx.x;

    // Bijective XCD-aware swizzle (m204 variant): each XCD gets a contiguous chunk of the
    // dst-sorted edge range -> q rows + num atomics stay in one XCD's L2.
    int nwg = gridDim.x;
    int q8 = nwg >> 3, r8 = nwg & 7;
    int xcd = blockIdx.x & 7, idx8 = blockIdx.x >> 3;
    int bid = (xcd < r8 ? xcd * (q8 + 1) : r8 * (q8 + 1) + (xcd - r8) * q8) + idx8;
    int e0 = bid * 64;

    if (tid < 64) {
        int e = e0 + tid;
        int s = 0, d = 0, p = 0;
        float rt = 0.f;
        if (e < E) {            // 4 independent coalesced loads, no dependent gather
            s = src_s[e];
            d = dst_s[e];
            p = perm[e];
            rt = relt_s[e];
        }
        s_src[tid] = s; s_dst[tid] = d; s_perm[tid] = p; s_relt[tid] = rt;
    }
    __syncthreads();

    // Stage edge_attr = [cos(rt*w+b) | msg] as bf16. cos half: 2 per 4B LDS write.
    // msg half: float4 loads (was scalar 4B), 8B LDS writes.
    {
        const float2* tw2 = (const float2*)time_w;
        const float2* tb2 = (const float2*)time_b;
        for (int i = tid; i < 64 * 32; i += 256) {
            int el = i >> 5, c2 = i & 31;
            float2 w = tw2[c2], b = tb2[c2];
            float rt = s_relt[el];
            unsigned int pk = ((unsigned int)f2bf(cosf(fmaf(rt, w.y, b.y))) << 16)
                            | f2bf(cosf(fmaf(rt, w.x, b.x)));
            *(unsigned int*)&sbuf[el][c2 * 2] = pk;
        }
        const float4* msg4 = (const float4*)msg;
        for (int j = tid; j < 64 * 16; j += 256) {
            int el = j >> 4, f4 = j & 15;
            float4 m = msg4[(size_t)s_perm[el] * 16 + f4];
            unsigned int lo = ((unsigned int)f2bf(m.y) << 16) | f2bf(m.x);
            unsigned int hi = ((unsigned int)f2bf(m.w) << 16) | f2bf(m.z);
            *(uint2*)&sbuf[el][TDIMC + f4 * 4] = make_uint2(lo, hi);
        }
    }
    __syncthreads();

    int lane = tid & 63;
    int wv = tid >> 6;            // wave -> edges wv*16 .. wv*16+15
    int n15 = lane & 15, quad = lane >> 4;

    ffrag acc[8];
#pragma unroll
    for (int c = 0; c < 8; ++c) acc[c] = (ffrag){0.f, 0.f, 0.f, 0.f};
#pragma unroll
    for (int kc = 0; kc < 4; ++kc) {
        int kk = kc * 32 + quad * 8;
        bfrag a = *(const bfrag*)&sbuf[wv * 16 + n15][kk];
#pragma unroll
        for (int c = 0; c < 8; ++c) {
            bfrag b = *(const bfrag*)&Wet[(c * 16 + n15) * 128 + kk];
            acc[c] = __builtin_amdgcn_mfma_f32_16x16x32_bf16(a, b, acc[c], 0, 0, 0);
        }
    }
    // Overlay e (bf16) onto this wave's rows. C layout: col=c*16+n15, row=quad*4+r.
#pragma unroll
    for (int c = 0; c < 8; ++c)
#pragma unroll
        for (int r = 0; r < 4; ++r)
            sbuf[wv * 16 + quad * 4 + r][c * 16 + n15] = (short)f2bf(acc[c][r]);

    __syncthreads();   // REQUIRED: orders overlay writes before cross-lane e reads

    // Phase 3: alpha + exp + fused segmented aggregation. Lane owns channels {2*lane, 2*lane+1}.
    int h = lane >> 5;            // head for this lane's channels
    float accx = 0.f, accy = 0.f, dacc = 0.f;
    int cur_d = s_dst[wv * 16];   // dst of first edge (uniform across wave)
#pragma unroll
    for (int jb = 0; jb < 16; jb += 4) {
        float2 kv[4], qv[4], vv[4];
        unsigned int ep[4];
        int sd[4], eidx[4];
#pragma unroll
        for (int u = 0; u < 4; ++u) {
            int el = wv * 16 + jb + u;
            eidx[u] = e0 + el;
            int s = s_src[el];
            sd[u] = s_dst[el];
            ep[u] = *(const unsigned int*)&sbuf[el][2 * lane];
            kv[u] = *(const float2*)&k[(size_t)s * CDIM + 2 * lane];
            qv[u] = *(const float2*)&q[(size_t)sd[u] * CDIM + 2 * lane];
            vv[u] = *(const float2*)&v[(size_t)s * CDIM + 2 * lane];
        }
#pragma unroll
        for (int u = 0; u < 4; ++u) {
            float ex0 = __uint_as_float(ep[u] << 16);
            float ex1 = __uint_as_float(ep[u] & 0xffff0000u);
            float kx = kv[u].x + ex0, ky = kv[u].y + ex1;
            float p = qv[u].x * kx + qv[u].y * ky;
#pragma unroll
            for (int off = 1; off < 32; off <<= 1) p += __shfl_xor(p, off, 32);
            // |alpha| bounded ~8 -> no seg-max needed; tail edges masked via exv=0
            float exv = (eidx[u] < E) ? expf(p * 0.125f) : 0.f;
            int d = sd[u];
            if (d != cur_d) {     // uniform across wave -> scalar branch
                float* np = &num[(size_t)cur_d * CDIM + 2 * lane];
                unsafeAtomicAdd(np, accx);
                unsafeAtomicAdd(np + 1, accy);
                if ((lane & 31) == 0) unsafeAtomicAdd(&den[cur_d * 2 + h], dacc);
                accx = 0.f; accy = 0.f; dacc = 0.f;
                cur_d = d;
            }
            float vx = vv[u].x + ex0, vy = vv[u].y + ex1;
            accx = fmaf(vx, exv, accx);
            accy = fmaf(vy, exv, accy);
            dacc += exv;
        }
    }
    {   // final flush
        float* np = &num[(size_t)cur_d * CDIM + 2 * lane];
        unsafeAtomicAdd(np, accx);
        unsafeAtomicAdd(np + 1, accy);
        if ((lane & 31) == 0) unsafeAtomicAdd(&den[cur_d * 2 + h], dacc);
    }
}

// ---------------- normalize: out += num / (den + eps) ----------------
__global__ __launch_bounds__(256)
void norm_kernel(const float* __restrict__ num, const float* __restrict__ den,
                 float* __restrict__ out, int N) {
    int idx = blockIdx.x * 256 + threadIdx.x;   // one float4 per thread
    if (idx >= N * 32) return;
    int n = idx >> 5, c4 = idx & 31;
    int h = c4 >> 4;                            // 4-chunks never cross the head boundary
    float inv = 1.f / (den[n * 2 + h] + 1e-16f);
    float4 nm = ((const float4*)num)[idx];
    float4* op = (float4*)out + idx;
    float4 o = *op;
    o.x = fmaf(nm.x, inv, o.x);
    o.y = fmaf(nm.y, inv, o.y);
    o.z = fmaf(nm.z, inv, o.z);
    o.w = fmaf(nm.w, inv, o.w);
    *op = o;
}

extern "C" void kernel_launch(void* const* d_in, const int* in_sizes, int n_in,
                              void* d_out, int out_size, void* d_ws, size_t ws_size,
                              hipStream_t stream) {
    const float* x       = (const float*)d_in[0];
    const int*   last_up = (const int*)d_in[1];
    const int*   ei      = (const int*)d_in[2];
    const int*   tarr    = (const int*)d_in[3];
    const float* msg     = (const float*)d_in[4];
    const float* time_w  = (const float*)d_in[5];
    const float* time_b  = (const float*)d_in[6];
    const float* Wq = (const float*)d_in[7];  const float* bq = (const float*)d_in[8];
    const float* Wk = (const float*)d_in[9];  const float* bk = (const float*)d_in[10];
    const float* Wv = (const float*)d_in[11]; const float* bv = (const float*)d_in[12];
    const float* We = (const float*)d_in[13];
    const float* Wskip = (const float*)d_in[14]; const float* bskip = (const float*)d_in[15];
    float* out = (float*)d_out;

    int N = in_sizes[0] / CDIM;
    int E = in_sizes[3];

    char* ws = (char*)d_ws;
    size_t off = 0;
#define ALLOC(ptr, type, nelem) type* ptr = (type*)(ws + off); off = (off + (size_t)(nelem) * sizeof(type) + 255) & ~(size_t)255
    ALLOC(q_,    float, (size_t)N * CDIM);
    ALLOC(k_,    float, (size_t)N * CDIM);
    ALLOC(v_,    float, (size_t)N * CDIM);
    ALLOC(num,   float, (size_t)N * CDIM + 2 * N);   // den lives right after num (one memset)
    float* den_ = num + (size_t)N * CDIM;
    ALLOC(count, int,   N + 64);          // flag lives right after count (one memset)
    int* flag = count + N;
    ALLOC(cur,    int,  N);
    ALLOC(perm,   int,  E);
    ALLOC(src_s,  int,  E);
    ALLOC(dst_s,  int,  E);
    ALLOC(relt_s, float, E);
    ALLOC(Wt,     short, 4 * 16384);
    ALLOC(Wet,    short, 16384);
#undef ALLOC

    // zero count + flag, and num + den (ws is poisoned 0xAA before each timed call)
    hipMemsetAsync(count, 0, (size_t)(N + 64) * 4, stream);
    hipMemsetAsync(num, 0, ((size_t)N * CDIM + 2 * N) * sizeof(float), stream);

    int samp = E < 65536 ? E : 65536;
    detect_kernel<<<(samp + 255) / 256, 256, 0, stream>>>(ei, samp, flag);
    hist_kernel<<<(E + 255) / 256, 256, 0, stream>>>(ei, E, flag, count);
    scan_kernel<<<1, 1024, 0, stream>>>(count, N, cur);
    scatter_kernel<<<(E + 255) / 256, 256, 0, stream>>>(ei, E, flag, tarr, last_up, cur,
                                                        perm, src_s, dst_s, relt_s);
    wconv_kernel<<<(5 * 16384 + 255) / 256, 256, 0, stream>>>(Wq, Wk, Wv, Wskip, We, Wt, Wet);
    proj_kernel<<<(N + 63) / 64, 256, 0, stream>>>(x, Wt, bq, bk, bv, bskip,
                                                   q_, k_, v_, out, N);
    edge_kernel<<<(E + 63) / 64, 256, 0, stream>>>(src_s, dst_s, relt_s, perm, msg,
                                                   time_w, time_b, Wet, q_, k_, v_,
                                                   num, den_, E);
    norm_kernel<<<(N * 32 + 255) / 256, 256, 0, stream>>>(num, den_, out, N);
}

// Round 2
// 629.330 us; speedup vs baseline: 1.4607x; 1.1501x over previous
//
#include <hip/hip_runtime.h>
#include <hip/hip_bf16.h>

typedef __hip_bfloat16 bf16;
typedef __attribute__((ext_vector_type(8))) short bfrag;   // 8 bf16 = 4 VGPRs
typedef __attribute__((ext_vector_type(4))) float ffrag;   // 4 fp32 acc

#define CDIM 128
#define TDIMC 64
#define MSGD 64
#define INV2PI 0.15915494309189535f

__device__ __forceinline__ unsigned short f2bf(float f) {
    union { __hip_bfloat16 h; unsigned short u; } cv;
    cv.h = __float2bfloat16(f);
    return cv.u;
}

// fast cos for pre-scaled (revolutions) argument: cos(2*pi*x)
__device__ __forceinline__ float fcos_rev(float xr) {
    float fr, c;
    asm("v_fract_f32 %0, %1" : "=v"(fr) : "v"(xr));   // [0,1) — v_cos takes revolutions
    asm("v_cos_f32 %0, %1" : "=v"(c) : "v"(fr));
    return c;
}

// ---------------- edge_index dtype detection ----------------
__global__ void detect_kernel(const int* __restrict__ ei, int samp, int* __restrict__ flag) {
    int i = blockIdx.x * blockDim.x + threadIdx.x;
    if (i < samp) {
        if (ei[2 * i + 1] != 0) atomicOr(flag, 1);   // int32 data -> odd words are dst values
    }
}

// ---------------- dst histogram straight from ei ----------------
__global__ void hist_kernel(const int* __restrict__ ei, int E, const int* __restrict__ flag,
                            int* __restrict__ count) {
    int e = blockIdx.x * 256 + threadIdx.x;
    if (e >= E) return;
    int is32 = *flag;
    int d = is32 ? ei[E + e] : ei[2 * (E + e)];   // int64 path: low word
    atomicAdd(&count[d], 1);
}

// ---------------- parallel scan: block-local pass ----------------
// cur[i] = exclusive scan of count within the 1024-block; bsum[b] = block total.
// Global offsets folded in at scatter time (pos += bsum_scanned[d>>10]).
__global__ __launch_bounds__(1024)
void scan1_kernel(const int* __restrict__ count, int N,
                  int* __restrict__ cur, int* __restrict__ bsum) {
    __shared__ int wsum[16];
    __shared__ int woff[16];
    int t = threadIdx.x;
    int lane = t & 63, wv = t >> 6;
    int i = blockIdx.x * 1024 + t;
    int v = (i < N) ? count[i] : 0;
    int incl = v;
#pragma unroll
    for (int off = 1; off < 64; off <<= 1) {
        int n = __shfl_up(incl, off, 64);
        if (lane >= off) incl += n;
    }
    if (lane == 63) wsum[wv] = incl;
    __syncthreads();
    if (wv == 0) {
        int ws = (lane < 16) ? wsum[lane] : 0;
        int wi = ws;
#pragma unroll
        for (int off = 1; off < 16; off <<= 1) {
            int n = __shfl_up(wi, off, 64);
            if (lane >= off) wi += n;
        }
        if (lane < 16) woff[lane] = wi - ws;   // exclusive wave offset
        if (lane == 15) bsum[blockIdx.x] = wi; // block total
    }
    __syncthreads();
    if (i < N) cur[i] = woff[wv] + incl - v;
}

// ---------------- parallel scan: scan the (<=64 at a time) block totals ----------------
__global__ void scan2_kernel(int* __restrict__ bsum, int nb) {
    int lane = threadIdx.x;   // launched with 64 threads
    int carry = 0;
    for (int base = 0; base < nb; base += 64) {
        int i = base + lane;
        int v = (i < nb) ? bsum[i] : 0;
        int incl = v;
#pragma unroll
        for (int off = 1; off < 64; off <<= 1) {
            int n = __shfl_up(incl, off, 64);
            if (lane >= off) incl += n;
        }
        if (i < nb) bsum[i] = carry + incl - v;   // exclusive
        carry += __shfl(incl, 63, 64);
    }
}

// ---------------- scatter into dst-sorted order (packed int4 rows) ----------------
// One 16B store per edge (1 dirty line, vs 4 scattered 4B stores = 4 lines).
// Also precomputes rel_t here (breaks the dependent-gather chain out of edge_kernel).
__global__ void scatter_kernel(const int* __restrict__ ei, int E, const int* __restrict__ flag,
                               const int* __restrict__ tarr, const int* __restrict__ last_update,
                               int* __restrict__ cur, const int* __restrict__ bsum,
                               int4* __restrict__ ed_s) {
    int e = blockIdx.x * 256 + threadIdx.x;
    if (e >= E) return;
    int is32 = *flag;
    int s = is32 ? ei[e] : ei[2 * e];
    int d = is32 ? ei[E + e] : ei[2 * (E + e)];
    int pos = atomicAdd(&cur[d], 1) + bsum[d >> 10];
    float rt = (float)(last_update[s] - tarr[e]);
    ed_s[pos] = make_int4(s, d, e, __float_as_int(rt));
}

// ---------------- weight pre-transpose + bf16 convert ----------------
__global__ void wconv_kernel(const float* __restrict__ Wq, const float* __restrict__ Wk,
                             const float* __restrict__ Wv, const float* __restrict__ Ws,
                             const float* __restrict__ We,
                             short* __restrict__ Wt, short* __restrict__ Wet) {
    int idx = blockIdx.x * 256 + threadIdx.x;
    if (idx >= 5 * 16384) return;
    int mat = idx >> 14;
    int r = idx & 16383;
    int n = r >> 7, kk = r & 127;
    const float* W = (mat == 0) ? Wq : (mat == 1) ? Wk : (mat == 2) ? Wv : (mat == 3) ? Ws : We;
    short bv = (short)f2bf(W[kk * 128 + n]);
    if (mat < 4) Wt[(size_t)mat * 16384 + n * 128 + kk] = bv;
    else         Wet[n * 128 + kk] = bv;
}

// ---------------- MFMA node projections: wave w -> {q,k,v,skip->out} ----------------
__global__ __launch_bounds__(256)
void proj_kernel(const float* __restrict__ x, const short* __restrict__ Wt,
                 const float* __restrict__ bq, const float* __restrict__ bk,
                 const float* __restrict__ bv, const float* __restrict__ bs,
                 float* __restrict__ q, float* __restrict__ k, float* __restrict__ v,
                 float* __restrict__ out, int N) {
    __shared__ __attribute__((aligned(16))) short sx[64][136];
    int tid = threadIdx.x;
    int n0 = blockIdx.x * 64;
    const float4* x4 = (const float4*)x;
    for (int i = tid; i < 64 * 32; i += 256) {
        int nl = i >> 5, c4 = i & 31;
        int n = n0 + nl;
        float4 f = (n < N) ? x4[(size_t)n * 32 + c4] : make_float4(0.f, 0.f, 0.f, 0.f);
        unsigned int lo = ((unsigned int)f2bf(f.y) << 16) | f2bf(f.x);
        unsigned int hi = ((unsigned int)f2bf(f.w) << 16) | f2bf(f.z);
        *(uint2*)&sx[nl][c4 * 4] = make_uint2(lo, hi);
    }
    __syncthreads();

    int lane = tid & 63, wv = tid >> 6;
    int n15 = lane & 15, quad = lane >> 4;
    const short* W = Wt + (size_t)wv * 16384;
    const float* bias = (wv == 0) ? bq : (wv == 1) ? bk : (wv == 2) ? bv : bs;
    float* dstp = (wv == 0) ? q : (wv == 1) ? k : (wv == 2) ? v : out;

    ffrag acc[4][8];
#pragma unroll
    for (int r = 0; r < 4; ++r)
#pragma unroll
        for (int c = 0; c < 8; ++c)
            acc[r][c] = (ffrag){0.f, 0.f, 0.f, 0.f};

#pragma unroll
    for (int kc = 0; kc < 4; ++kc) {
        int kk = kc * 32 + quad * 8;
        bfrag a[4];
#pragma unroll
        for (int r = 0; r < 4; ++r)
            a[r] = *(const bfrag*)&sx[r * 16 + n15][kk];
#pragma unroll
        for (int c = 0; c < 8; ++c) {
            bfrag b = *(const bfrag*)&W[(c * 16 + n15) * 128 + kk];
#pragma unroll
            for (int r = 0; r < 4; ++r)
                acc[r][c] = __builtin_amdgcn_mfma_f32_16x16x32_bf16(a[r], b, acc[r][c], 0, 0, 0);
        }
    }

#pragma unroll
    for (int c = 0; c < 8; ++c) {
        int col = c * 16 + n15;
        float bval = bias[col];
#pragma unroll
        for (int r = 0; r < 4; ++r) {
#pragma unroll
            for (int g = 0; g < 4; ++g) {
                int n = n0 + r * 16 + quad * 4 + g;
                if (n < N) dstp[(size_t)n * CDIM + col] = acc[r][c][g] + bval;
            }
        }
    }
}

// ---------------- MFMA edge kernel, fused segment-softmax aggregation ----------------
// Block = 64 dst-sorted edges, 4 waves x 16 edges. sbuf: edge_attr staged, e overlaid.
// Overlay WRITE needs no barrier (depends on all A-frag ds_reads via the MFMA chain);
// phase-3 READ of e needs the barrier (SIMT race otherwise).
// Phase 3 software pipeline: batches 0-1 prefetched before the overlay barrier (hidden
// under MFMA), then LOAD(2)/PROC(0)/LOAD(3)/PROC(1)/PROC(2)/PROC(3) — 2-batch distance.
#define LOADQ(KA, QA, VA, JB) do {                                              \
    _Pragma("unroll")                                                           \
    for (int u = 0; u < 4; ++u) {                                               \
        int el = wv * 16 + (JB) * 4 + u;                                        \
        int s = s_src[el], d = s_dst[el];                                       \
        KA[u] = *(const float2*)&k[(size_t)s * CDIM + 2 * lane];                \
        QA[u] = *(const float2*)&q[(size_t)d * CDIM + 2 * lane];                \
        VA[u] = *(const float2*)&v[(size_t)s * CDIM + 2 * lane];                \
    } } while (0)

#define PROC(KA, QA, VA, JB) do {                                               \
    _Pragma("unroll")                                                           \
    for (int u = 0; u < 4; ++u) {                                               \
        int el = wv * 16 + (JB) * 4 + u;                                        \
        unsigned int ep = *(const unsigned int*)&sbuf[el][2 * lane];            \
        float ex0 = __uint_as_float(ep << 16);                                  \
        float ex1 = __uint_as_float(ep & 0xffff0000u);                          \
        float kx = KA[u].x + ex0, ky = KA[u].y + ex1;                           \
        float p = QA[u].x * kx + QA[u].y * ky;                                  \
        _Pragma("unroll")                                                       \
        for (int off = 1; off < 32; off <<= 1) p += __shfl_xor(p, off, 32);     \
        float exv = (e0 + el < E) ? __expf(p * 0.125f) : 0.f;                   \
        int d = s_dst[el];                                                      \
        if (d != cur_d) {   /* uniform across wave */                           \
            float* np = &num[(size_t)cur_d * CDIM + 2 * lane];                  \
            unsafeAtomicAdd(np, accx);                                          \
            unsafeAtomicAdd(np + 1, accy);                                      \
            if ((lane & 31) == 0) unsafeAtomicAdd(&den[cur_d * 2 + h], dacc);   \
            accx = 0.f; accy = 0.f; dacc = 0.f;                                 \
            cur_d = d;                                                          \
        }                                                                       \
        float vx = VA[u].x + ex0, vy = VA[u].y + ex1;                           \
        accx = fmaf(vx, exv, accx);                                             \
        accy = fmaf(vy, exv, accy);                                             \
        dacc += exv;                                                            \
    } } while (0)

__global__ __launch_bounds__(256)
void edge_kernel(const int4* __restrict__ ed_s,
                 const float* __restrict__ msg,
                 const float* __restrict__ time_w, const float* __restrict__ time_b,
                 const short* __restrict__ Wet,
                 const float* __restrict__ q, const float* __restrict__ k, const float* __restrict__ v,
                 float* __restrict__ num, float* __restrict__ den,
                 int E) {
    __shared__ __attribute__((aligned(16))) short sbuf[64][136];
    __shared__ int s_src[64], s_dst[64];
    int tid = threadIdx.x;

    // Bijective XCD-aware swizzle: each XCD owns a contiguous chunk of dst-sorted edges.
    int nwg = gridDim.x;
    int q8 = nwg >> 3, r8 = nwg & 7;
    int xcd = blockIdx.x & 7, idx8 = blockIdx.x >> 3;
    int bid = (xcd < r8 ? xcd * (q8 + 1) : r8 * (q8 + 1) + (xcd - r8) * q8) + idx8;
    int e0 = bid * 64;

    // Phase A: stage edge meta into LDS (wave 0) + edge_attr staging. ed_s has a
    // zeroed 64-entry tail, so no bounds checks needed on these reads.
    if (tid < 64) {
        int4 ed = ed_s[e0 + tid];
        s_src[tid] = ed.x;
        s_dst[tid] = ed.y;
    }
    {   // cos half: fast revolutions-space cos (ref's own arg rounding is same order)
#pragma unroll
        for (int ii = 0; ii < 8; ++ii) {
            int i = tid + ii * 256;
            int el = i >> 5, c2 = i & 31;
            float rt = __int_as_float(ed_s[e0 + el].w);
            float2 w = ((const float2*)time_w)[c2];
            float2 b = ((const float2*)time_b)[c2];
            float c0 = fcos_rev(fmaf(rt, w.x * INV2PI, b.x * INV2PI));
            float c1 = fcos_rev(fmaf(rt, w.y * INV2PI, b.y * INV2PI));
            unsigned int pk = ((unsigned int)f2bf(c1) << 16) | f2bf(c0);
            *(unsigned int*)&sbuf[el][c2 * 2] = pk;
        }
        const float4* msg4 = (const float4*)msg;
#pragma unroll
        for (int jj = 0; jj < 4; ++jj) {
            int j = tid + jj * 256;
            int el = j >> 4, f4 = j & 15;
            int p = ed_s[e0 + el].z;
            float4 m = msg4[(size_t)p * 16 + f4];
            unsigned int lo = ((unsigned int)f2bf(m.y) << 16) | f2bf(m.x);
            unsigned int hi = ((unsigned int)f2bf(m.w) << 16) | f2bf(m.z);
            *(uint2*)&sbuf[el][TDIMC + f4 * 4] = make_uint2(lo, hi);
        }
    }
    __syncthreads();

    int lane = tid & 63;
    int wv = tid >> 6;            // wave -> edges wv*16 .. wv*16+15
    int n15 = lane & 15, quad = lane >> 4;

    // Prefetch phase-3 batches 0,1 — latency hides under the MFMA phase.
    float2 k0[4], q0[4], v0[4], k1[4], q1[4], v1[4];
    float2 k2[4], q2[4], v2[4], k3[4], q3[4], v3[4];
    LOADQ(k0, q0, v0, 0);
    LOADQ(k1, q1, v1, 1);

    ffrag acc[8];
#pragma unroll
    for (int c = 0; c < 8; ++c) acc[c] = (ffrag){0.f, 0.f, 0.f, 0.f};
#pragma unroll
    for (int kc = 0; kc < 4; ++kc) {
        int kk = kc * 32 + quad * 8;
        bfrag a = *(const bfrag*)&sbuf[wv * 16 + n15][kk];
#pragma unroll
        for (int c = 0; c < 8; ++c) {
            bfrag b = *(const bfrag*)&Wet[(c * 16 + n15) * 128 + kk];
            acc[c] = __builtin_amdgcn_mfma_f32_16x16x32_bf16(a, b, acc[c], 0, 0, 0);
        }
    }
    // Overlay e (bf16) onto this wave's rows. C layout: col=c*16+n15, row=quad*4+r.
#pragma unroll
    for (int c = 0; c < 8; ++c)
#pragma unroll
        for (int r = 0; r < 4; ++r)
            sbuf[wv * 16 + quad * 4 + r][c * 16 + n15] = (short)f2bf(acc[c][r]);

    __syncthreads();   // REQUIRED: orders overlay writes before cross-lane e reads

    // Phase 3: alpha + exp + fused segmented aggregation. Lane owns channels {2*lane, 2*lane+1}.
    int h = lane >> 5;
    float accx = 0.f, accy = 0.f, dacc = 0.f;
    int cur_d = s_dst[wv * 16];

    LOADQ(k2, q2, v2, 2);
    PROC(k0, q0, v0, 0);
    LOADQ(k3, q3, v3, 3);
    PROC(k1, q1, v1, 1);
    PROC(k2, q2, v2, 2);
    PROC(k3, q3, v3, 3);

    {   // final flush
        float* np = &num[(size_t)cur_d * CDIM + 2 * lane];
        unsafeAtomicAdd(np, accx);
        unsafeAtomicAdd(np + 1, accy);
        if ((lane & 31) == 0) unsafeAtomicAdd(&den[cur_d * 2 + h], dacc);
    }
}

// ---------------- normalize: out += num / (den + eps) ----------------
__global__ __launch_bounds__(256)
void norm_kernel(const float* __restrict__ num, const float* __restrict__ den,
                 float* __restrict__ out, int N) {
    int idx = blockIdx.x * 256 + threadIdx.x;   // one float4 per thread
    if (idx >= N * 32) return;
    int n = idx >> 5, c4 = idx & 31;
    int h = c4 >> 4;                            // 4-chunks never cross the head boundary
    float inv = 1.f / (den[n * 2 + h] + 1e-16f);
    float4 nm = ((const float4*)num)[idx];
    float4* op = (float4*)out + idx;
    float4 o = *op;
    o.x = fmaf(nm.x, inv, o.x);
    o.y = fmaf(nm.y, inv, o.y);
    o.z = fmaf(nm.z, inv, o.z);
    o.w = fmaf(nm.w, inv, o.w);
    *op = o;
}

extern "C" void kernel_launch(void* const* d_in, const int* in_sizes, int n_in,
                              void* d_out, int out_size, void* d_ws, size_t ws_size,
                              hipStream_t stream) {
    const float* x       = (const float*)d_in[0];
    const int*   last_up = (const int*)d_in[1];
    const int*   ei      = (const int*)d_in[2];
    const int*   tarr    = (const int*)d_in[3];
    const float* msg     = (const float*)d_in[4];
    const float* time_w  = (const float*)d_in[5];
    const float* time_b  = (const float*)d_in[6];
    const float* Wq = (const float*)d_in[7];  const float* bq = (const float*)d_in[8];
    const float* Wk = (const float*)d_in[9];  const float* bk = (const float*)d_in[10];
    const float* Wv = (const float*)d_in[11]; const float* bv = (const float*)d_in[12];
    const float* We = (const float*)d_in[13];
    const float* Wskip = (const float*)d_in[14]; const float* bskip = (const float*)d_in[15];
    float* out = (float*)d_out;

    int N = in_sizes[0] / CDIM;
    int E = in_sizes[3];
    int nb = (N + 1023) >> 10;

    char* ws = (char*)d_ws;
    size_t off = 0;
#define ALLOC(ptr, type, nelem) type* ptr = (type*)(ws + off); off = (off + (size_t)(nelem) * sizeof(type) + 255) & ~(size_t)255
    ALLOC(q_,    float, (size_t)N * CDIM);
    ALLOC(k_,    float, (size_t)N * CDIM);
    ALLOC(v_,    float, (size_t)N * CDIM);
    ALLOC(num,   float, (size_t)N * CDIM + 2 * N);   // den lives right after num (one memset)
    float* den_ = num + (size_t)N * CDIM;
    ALLOC(count, int,   N + 64);          // flag lives right after count (one memset)
    int* flag = count + N;
    ALLOC(cur,    int,  N);
    ALLOC(bsum,   int,  nb + 64);
    ALLOC(ed_s,   int4, (size_t)E + 64);  // 64-entry zeroed tail for guard-free reads
    ALLOC(Wt,     short, 4 * 16384);
    ALLOC(Wet,    short, 16384);
#undef ALLOC

    // zero count + flag, num + den, and the ed_s tail (ws is poisoned before each call)
    hipMemsetAsync(count, 0, (size_t)(N + 64) * 4, stream);
    hipMemsetAsync(num, 0, ((size_t)N * CDIM + 2 * N) * sizeof(float), stream);
    hipMemsetAsync(ed_s + E, 0, 64 * sizeof(int4), stream);

    int samp = E < 65536 ? E : 65536;
    detect_kernel<<<(samp + 255) / 256, 256, 0, stream>>>(ei, samp, flag);
    hist_kernel<<<(E + 255) / 256, 256, 0, stream>>>(ei, E, flag, count);
    scan1_kernel<<<nb, 1024, 0, stream>>>(count, N, cur, bsum);
    scan2_kernel<<<1, 64, 0, stream>>>(bsum, nb);
    scatter_kernel<<<(E + 255) / 256, 256, 0, stream>>>(ei, E, flag, tarr, last_up,
                                                        cur, bsum, ed_s);
    wconv_kernel<<<(5 * 16384 + 255) / 256, 256, 0, stream>>>(Wq, Wk, Wv, Wskip, We, Wt, Wet);
    proj_kernel<<<(N + 63) / 64, 256, 0, stream>>>(x, Wt, bq, bk, bv, bskip,
                                                   q_, k_, v_, out, N);
    edge_kernel<<<(E + 63) / 64, 256, 0, stream>>>(ed_s, msg, time_w, time_b, Wet,
                                                   q_, k_, v_, num, den_, E);
    norm_kernel<<<(N * 32 + 255) / 256, 256, 0, stream>>>(num, den_, out, N);
}

// Round 3
// 624.498 us; speedup vs baseline: 1.4720x; 1.0077x over previous
//
#include <hip/hip_runtime.h>
#include <hip/hip_bf16.h>

typedef __hip_bfloat16 bf16;
typedef __attribute__((ext_vector_type(8))) short bfrag;   // 8 bf16 = 4 VGPRs
typedef __attribute__((ext_vector_type(4))) float ffrag;   // 4 fp32 acc

#define CDIM 128
#define TDIMC 64
#define MSGD 64
#define INV2PI 0.15915494309189535f

__device__ __forceinline__ unsigned short f2bf(float f) {
    union { __hip_bfloat16 h; unsigned short u; } cv;
    cv.h = __float2bfloat16(f);
    return cv.u;
}

// fast cos for pre-scaled (revolutions) argument: cos(2*pi*x)
__device__ __forceinline__ float fcos_rev(float xr) {
    float fr, c;
    asm("v_fract_f32 %0, %1" : "=v"(fr) : "v"(xr));   // [0,1) — v_cos takes revolutions
    asm("v_cos_f32 %0, %1" : "=v"(c) : "v"(fr));
    return c;
}

// ---------------- edge_index dtype detection ----------------
__global__ void detect_kernel(const int* __restrict__ ei, int samp, int* __restrict__ flag) {
    int i = blockIdx.x * blockDim.x + threadIdx.x;
    if (i < samp) {
        if (ei[2 * i + 1] != 0) atomicOr(flag, 1);   // int32 data -> odd words are dst values
    }
}

// ---------------- dst histogram straight from ei ----------------
__global__ void hist_kernel(const int* __restrict__ ei, int E, const int* __restrict__ flag,
                            int* __restrict__ count) {
    int e = blockIdx.x * 256 + threadIdx.x;
    if (e >= E) return;
    int is32 = *flag;
    int d = is32 ? ei[E + e] : ei[2 * (E + e)];   // int64 path: low word
    atomicAdd(&count[d], 1);
}

// ---------------- parallel scan: block-local pass ----------------
__global__ __launch_bounds__(1024)
void scan1_kernel(const int* __restrict__ count, int N,
                  int* __restrict__ cur, int* __restrict__ bsum) {
    __shared__ int wsum[16];
    __shared__ int woff[16];
    int t = threadIdx.x;
    int lane = t & 63, wv = t >> 6;
    int i = blockIdx.x * 1024 + t;
    int v = (i < N) ? count[i] : 0;
    int incl = v;
#pragma unroll
    for (int off = 1; off < 64; off <<= 1) {
        int n = __shfl_up(incl, off, 64);
        if (lane >= off) incl += n;
    }
    if (lane == 63) wsum[wv] = incl;
    __syncthreads();
    if (wv == 0) {
        int ws = (lane < 16) ? wsum[lane] : 0;
        int wi = ws;
#pragma unroll
        for (int off = 1; off < 16; off <<= 1) {
            int n = __shfl_up(wi, off, 64);
            if (lane >= off) wi += n;
        }
        if (lane < 16) woff[lane] = wi - ws;   // exclusive wave offset
        if (lane == 15) bsum[blockIdx.x] = wi; // block total
    }
    __syncthreads();
    if (i < N) cur[i] = woff[wv] + incl - v;
}

// ---------------- parallel scan: scan the block totals ----------------
__global__ void scan2_kernel(int* __restrict__ bsum, int nb) {
    int lane = threadIdx.x;   // launched with 64 threads
    int carry = 0;
    for (int base = 0; base < nb; base += 64) {
        int i = base + lane;
        int v = (i < nb) ? bsum[i] : 0;
        int incl = v;
#pragma unroll
        for (int off = 1; off < 64; off <<= 1) {
            int n = __shfl_up(incl, off, 64);
            if (lane >= off) incl += n;
        }
        if (i < nb) bsum[i] = carry + incl - v;   // exclusive
        carry += __shfl(incl, 63, 64);
    }
}

// ---------------- scatter into dst-sorted order (packed int4 rows) ----------------
__global__ void scatter_kernel(const int* __restrict__ ei, int E, const int* __restrict__ flag,
                               const int* __restrict__ tarr, const int* __restrict__ last_update,
                               int* __restrict__ cur, const int* __restrict__ bsum,
                               int4* __restrict__ ed_s) {
    int e = blockIdx.x * 256 + threadIdx.x;
    if (e >= E) return;
    int is32 = *flag;
    int s = is32 ? ei[e] : ei[2 * e];
    int d = is32 ? ei[E + e] : ei[2 * (E + e)];
    int pos = atomicAdd(&cur[d], 1) + bsum[d >> 10];
    float rt = (float)(last_update[s] - tarr[e]);
    ed_s[pos] = make_int4(s, d, e, __float_as_int(rt));
}

// ---------------- weight pre-transpose + bf16 convert ----------------
__global__ void wconv_kernel(const float* __restrict__ Wq, const float* __restrict__ Wk,
                             const float* __restrict__ Wv, const float* __restrict__ Ws,
                             const float* __restrict__ We,
                             short* __restrict__ Wt, short* __restrict__ Wet) {
    int idx = blockIdx.x * 256 + threadIdx.x;
    if (idx >= 5 * 16384) return;
    int mat = idx >> 14;
    int r = idx & 16383;
    int n = r >> 7, kk = r & 127;
    const float* W = (mat == 0) ? Wq : (mat == 1) ? Wk : (mat == 2) ? Wv : (mat == 3) ? Ws : We;
    short bv = (short)f2bf(W[kk * 128 + n]);
    if (mat < 4) Wt[(size_t)mat * 16384 + n * 128 + kk] = bv;
    else         Wet[n * 128 + kk] = bv;
}

// ---------------- MFMA node projections: wave w -> {q(f32), k(bf16), v(bf16), skip(f32)->out}
__global__ __launch_bounds__(256)
void proj_kernel(const float* __restrict__ x, const short* __restrict__ Wt,
                 const float* __restrict__ bq, const float* __restrict__ bk,
                 const float* __restrict__ bv, const float* __restrict__ bs,
                 float* __restrict__ q, short* __restrict__ kbf, short* __restrict__ vbf,
                 float* __restrict__ out, int N) {
    __shared__ __attribute__((aligned(16))) short sx[64][136];
    int tid = threadIdx.x;
    int n0 = blockIdx.x * 64;
    const float4* x4 = (const float4*)x;
    for (int i = tid; i < 64 * 32; i += 256) {
        int nl = i >> 5, c4 = i & 31;
        int n = n0 + nl;
        float4 f = (n < N) ? x4[(size_t)n * 32 + c4] : make_float4(0.f, 0.f, 0.f, 0.f);
        unsigned int lo = ((unsigned int)f2bf(f.y) << 16) | f2bf(f.x);
        unsigned int hi = ((unsigned int)f2bf(f.w) << 16) | f2bf(f.z);
        *(uint2*)&sx[nl][c4 * 4] = make_uint2(lo, hi);
    }
    __syncthreads();

    int lane = tid & 63, wv = tid >> 6;
    int n15 = lane & 15, quad = lane >> 4;
    const short* W = Wt + (size_t)wv * 16384;
    const float* bias = (wv == 0) ? bq : (wv == 1) ? bk : (wv == 2) ? bv : bs;

    ffrag acc[4][8];
#pragma unroll
    for (int r = 0; r < 4; ++r)
#pragma unroll
        for (int c = 0; c < 8; ++c)
            acc[r][c] = (ffrag){0.f, 0.f, 0.f, 0.f};

#pragma unroll
    for (int kc = 0; kc < 4; ++kc) {
        int kk = kc * 32 + quad * 8;
        bfrag a[4];
#pragma unroll
        for (int r = 0; r < 4; ++r)
            a[r] = *(const bfrag*)&sx[r * 16 + n15][kk];
#pragma unroll
        for (int c = 0; c < 8; ++c) {
            bfrag b = *(const bfrag*)&W[(c * 16 + n15) * 128 + kk];
#pragma unroll
            for (int r = 0; r < 4; ++r)
                acc[r][c] = __builtin_amdgcn_mfma_f32_16x16x32_bf16(a[r], b, acc[r][c], 0, 0, 0);
        }
    }

    if (wv == 1 || wv == 2) {          // k, v -> bf16 (halves edge-gather bytes)
        short* dsts = (wv == 1) ? kbf : vbf;
#pragma unroll
        for (int c = 0; c < 8; ++c) {
            int col = c * 16 + n15;
            float bval = bias[col];
#pragma unroll
            for (int r = 0; r < 4; ++r) {
#pragma unroll
                for (int g = 0; g < 4; ++g) {
                    int n = n0 + r * 16 + quad * 4 + g;
                    if (n < N) dsts[(size_t)n * CDIM + col] = (short)f2bf(acc[r][c][g] + bval);
                }
            }
        }
    } else {                           // q, skip -> f32
        float* dstp = (wv == 0) ? q : out;
#pragma unroll
        for (int c = 0; c < 8; ++c) {
            int col = c * 16 + n15;
            float bval = bias[col];
#pragma unroll
            for (int r = 0; r < 4; ++r) {
#pragma unroll
                for (int g = 0; g < 4; ++g) {
                    int n = n0 + r * 16 + quad * 4 + g;
                    if (n < N) dstp[(size_t)n * CDIM + col] = acc[r][c][g] + bval;
                }
            }
        }
    }
}

// ---------------- MFMA edge kernel, fused segment-softmax aggregation ----------------
// Block = 64 dst-sorted edges, 4 waves x 16 edges. sbuf: edge_attr staged, e overlaid.
// Overlay WRITE needs no barrier (depends on all A-frag ds_reads via the MFMA chain);
// the phase-3 READ of e needs a barrier. We use raw s_barrier + lgkmcnt(0) (NOT
// __syncthreads) so the prefetched batch-0/1 global loads stay in flight across it
// (no vmcnt(0) drain); sched_barrier(0) pins the ds ops around it (rule #18).
#define LOADQ(KA, QA, VA, JB) do {                                              \
    _Pragma("unroll")                                                           \
    for (int u = 0; u < 4; ++u) {                                               \
        int el = wv * 16 + (JB) * 4 + u;                                        \
        int s = s_src[el], d = s_dst[el];                                       \
        KA[u] = *(const unsigned int*)&k[(size_t)s * CDIM + 2 * lane];          \
        QA[u] = *(const float2*)&q[(size_t)d * CDIM + 2 * lane];                \
        VA[u] = *(const unsigned int*)&v[(size_t)s * CDIM + 2 * lane];          \
    } } while (0)

#define PROC(KA, QA, VA, JB) do {                                               \
    _Pragma("unroll")                                                           \
    for (int u = 0; u < 4; ++u) {                                               \
        int el = wv * 16 + (JB) * 4 + u;                                        \
        unsigned int ep = *(const unsigned int*)&sbuf[el][2 * lane];            \
        float ex0 = __uint_as_float(ep << 16);                                  \
        float ex1 = __uint_as_float(ep & 0xffff0000u);                          \
        float kx = __uint_as_float(KA[u] << 16) + ex0;                          \
        float ky = __uint_as_float(KA[u] & 0xffff0000u) + ex1;                  \
        float p = QA[u].x * kx + QA[u].y * ky;                                  \
        _Pragma("unroll")                                                       \
        for (int off = 1; off < 32; off <<= 1) p += __shfl_xor(p, off, 32);     \
        float exv = (e0 + el < E) ? __expf(p * 0.125f) : 0.f;                   \
        int d = s_dst[el];                                                      \
        if (d != cur_d) {   /* uniform across wave */                           \
            float* np = &num[(size_t)cur_d * CDIM + 2 * lane];                  \
            unsafeAtomicAdd(np, accx);                                          \
            unsafeAtomicAdd(np + 1, accy);                                      \
            if ((lane & 31) == 0) unsafeAtomicAdd(&den[cur_d * 2 + h], dacc);   \
            accx = 0.f; accy = 0.f; dacc = 0.f;                                 \
            cur_d = d;                                                          \
        }                                                                       \
        float vx = __uint_as_float(VA[u] << 16) + ex0;                          \
        float vy = __uint_as_float(VA[u] & 0xffff0000u) + ex1;                  \
        accx = fmaf(vx, exv, accx);                                             \
        accy = fmaf(vy, exv, accy);                                             \
        dacc += exv;                                                            \
    } } while (0)

__global__ __launch_bounds__(256)
void edge_kernel(const int4* __restrict__ ed_s,
                 const float* __restrict__ msg,
                 const float* __restrict__ time_w, const float* __restrict__ time_b,
                 const short* __restrict__ Wet,
                 const float* __restrict__ q, const short* __restrict__ k, const short* __restrict__ v,
                 float* __restrict__ num, float* __restrict__ den,
                 int E) {
    __shared__ __attribute__((aligned(16))) short sbuf[64][136];
    __shared__ int s_src[64], s_dst[64];
    int tid = threadIdx.x;

    // Bijective XCD-aware swizzle: each XCD owns a contiguous chunk of dst-sorted edges.
    int nwg = gridDim.x;
    int q8 = nwg >> 3, r8 = nwg & 7;
    int xcd = blockIdx.x & 7, idx8 = blockIdx.x >> 3;
    int bid = (xcd < r8 ? xcd * (q8 + 1) : r8 * (q8 + 1) + (xcd - r8) * q8) + idx8;
    int e0 = bid * 64;

    // Phase A: stage edge meta + edge_attr. ed_s has a zeroed 64-entry tail.
    if (tid < 64) {
        int4 ed = ed_s[e0 + tid];
        s_src[tid] = ed.x;
        s_dst[tid] = ed.y;
    }
    {   // cos half: fast revolutions-space cos
#pragma unroll
        for (int ii = 0; ii < 8; ++ii) {
            int i = tid + ii * 256;
            int el = i >> 5, c2 = i & 31;
            float rt = __int_as_float(ed_s[e0 + el].w);
            float2 w = ((const float2*)time_w)[c2];
            float2 b = ((const float2*)time_b)[c2];
            float c0 = fcos_rev(fmaf(rt, w.x * INV2PI, b.x * INV2PI));
            float c1 = fcos_rev(fmaf(rt, w.y * INV2PI, b.y * INV2PI));
            unsigned int pk = ((unsigned int)f2bf(c1) << 16) | f2bf(c0);
            *(unsigned int*)&sbuf[el][c2 * 2] = pk;
        }
        const float4* msg4 = (const float4*)msg;
#pragma unroll
        for (int jj = 0; jj < 4; ++jj) {
            int j = tid + jj * 256;
            int el = j >> 4, f4 = j & 15;
            int p = ed_s[e0 + el].z;
            float4 m = msg4[(size_t)p * 16 + f4];
            unsigned int lo = ((unsigned int)f2bf(m.y) << 16) | f2bf(m.x);
            unsigned int hi = ((unsigned int)f2bf(m.w) << 16) | f2bf(m.z);
            *(uint2*)&sbuf[el][TDIMC + f4 * 4] = make_uint2(lo, hi);
        }
    }
    __syncthreads();

    int lane = tid & 63;
    int wv = tid >> 6;            // wave -> edges wv*16 .. wv*16+15
    int n15 = lane & 15, quad = lane >> 4;

    // Prefetch phase-3 batches 0,1 — latency hides under the MFMA phase AND survives
    // the overlay barrier (no vmcnt drain there).
    unsigned int k0[4], v0[4], k1[4], v1[4], k2[4], v2[4], k3[4], v3[4];
    float2 q0[4], q1[4], q2[4], q3[4];
    LOADQ(k0, q0, v0, 0);
    LOADQ(k1, q1, v1, 1);

    ffrag acc[8];
#pragma unroll
    for (int c = 0; c < 8; ++c) acc[c] = (ffrag){0.f, 0.f, 0.f, 0.f};
#pragma unroll
    for (int kc = 0; kc < 4; ++kc) {
        int kk = kc * 32 + quad * 8;
        bfrag a = *(const bfrag*)&sbuf[wv * 16 + n15][kk];
#pragma unroll
        for (int c = 0; c < 8; ++c) {
            bfrag b = *(const bfrag*)&Wet[(c * 16 + n15) * 128 + kk];
            acc[c] = __builtin_amdgcn_mfma_f32_16x16x32_bf16(a, b, acc[c], 0, 0, 0);
        }
    }
    // Overlay e (bf16) onto this wave's rows. C layout: col=c*16+n15, row=quad*4+r.
#pragma unroll
    for (int c = 0; c < 8; ++c)
#pragma unroll
        for (int r = 0; r < 4; ++r)
            sbuf[wv * 16 + quad * 4 + r][c * 16 + n15] = (short)f2bf(acc[c][r]);

    // Barrier WITHOUT vmcnt drain: order LDS overlay writes (lgkmcnt) then s_barrier.
    asm volatile("s_waitcnt lgkmcnt(0)" ::: "memory");
    __builtin_amdgcn_s_barrier();
    __builtin_amdgcn_sched_barrier(0);

    // Phase 3: alpha + exp + fused segmented aggregation. Lane owns channels {2*lane, 2*lane+1}.
    int h = lane >> 5;
    float accx = 0.f, accy = 0.f, dacc = 0.f;
    int cur_d = s_dst[wv * 16];

    LOADQ(k2, q2, v2, 2);
    PROC(k0, q0, v0, 0);
    LOADQ(k3, q3, v3, 3);
    PROC(k1, q1, v1, 1);
    PROC(k2, q2, v2, 2);
    PROC(k3, q3, v3, 3);

    {   // final flush
        float* np = &num[(size_t)cur_d * CDIM + 2 * lane];
        unsafeAtomicAdd(np, accx);
        unsafeAtomicAdd(np + 1, accy);
        if ((lane & 31) == 0) unsafeAtomicAdd(&den[cur_d * 2 + h], dacc);
    }
}

// ---------------- normalize: out += num / (den + eps) ----------------
__global__ __launch_bounds__(256)
void norm_kernel(const float* __restrict__ num, const float* __restrict__ den,
                 float* __restrict__ out, int N) {
    int idx = blockIdx.x * 256 + threadIdx.x;   // one float4 per thread
    if (idx >= N * 32) return;
    int n = idx >> 5, c4 = idx & 31;
    int h = c4 >> 4;                            // 4-chunks never cross the head boundary
    float inv = 1.f / (den[n * 2 + h] + 1e-16f);
    float4 nm = ((const float4*)num)[idx];
    float4* op = (float4*)out + idx;
    float4 o = *op;
    o.x = fmaf(nm.x, inv, o.x);
    o.y = fmaf(nm.y, inv, o.y);
    o.z = fmaf(nm.z, inv, o.z);
    o.w = fmaf(nm.w, inv, o.w);
    *op = o;
}

extern "C" void kernel_launch(void* const* d_in, const int* in_sizes, int n_in,
                              void* d_out, int out_size, void* d_ws, size_t ws_size,
                              hipStream_t stream) {
    const float* x       = (const float*)d_in[0];
    const int*   last_up = (const int*)d_in[1];
    const int*   ei      = (const int*)d_in[2];
    const int*   tarr    = (const int*)d_in[3];
    const float* msg     = (const float*)d_in[4];
    const float* time_w  = (const float*)d_in[5];
    const float* time_b  = (const float*)d_in[6];
    const float* Wq = (const float*)d_in[7];  const float* bq = (const float*)d_in[8];
    const float* Wk = (const float*)d_in[9];  const float* bk = (const float*)d_in[10];
    const float* Wv = (const float*)d_in[11]; const float* bv = (const float*)d_in[12];
    const float* We = (const float*)d_in[13];
    const float* Wskip = (const float*)d_in[14]; const float* bskip = (const float*)d_in[15];
    float* out = (float*)d_out;

    int N = in_sizes[0] / CDIM;
    int E = in_sizes[3];
    int nb = (N + 1023) >> 10;

    char* ws = (char*)d_ws;
    size_t off = 0;
#define ALLOC(ptr, type, nelem) type* ptr = (type*)(ws + off); off = (off + (size_t)(nelem) * sizeof(type) + 255) & ~(size_t)255
    ALLOC(q_,    float, (size_t)N * CDIM);
    ALLOC(kbf_,  short, (size_t)N * CDIM);
    ALLOC(vbf_,  short, (size_t)N * CDIM);
    ALLOC(num,   float, (size_t)N * CDIM + 2 * N);   // den lives right after num (one memset)
    float* den_ = num + (size_t)N * CDIM;
    ALLOC(count, int,   N + 64);          // flag lives right after count (one memset)
    int* flag = count + N;
    ALLOC(cur,    int,  N);
    ALLOC(bsum,   int,  nb + 64);
    ALLOC(ed_s,   int4, (size_t)E + 64);  // 64-entry zeroed tail for guard-free reads
    ALLOC(Wt,     short, 4 * 16384);
    ALLOC(Wet,    short, 16384);
#undef ALLOC

    // zero count + flag, num + den, and the ed_s tail (ws is poisoned before each call)
    hipMemsetAsync(count, 0, (size_t)(N + 64) * 4, stream);
    hipMemsetAsync(num, 0, ((size_t)N * CDIM + 2 * N) * sizeof(float), stream);
    hipMemsetAsync(ed_s + E, 0, 64 * sizeof(int4), stream);

    int samp = E < 65536 ? E : 65536;
    detect_kernel<<<(samp + 255) / 256, 256, 0, stream>>>(ei, samp, flag);
    hist_kernel<<<(E + 255) / 256, 256, 0, stream>>>(ei, E, flag, count);
    scan1_kernel<<<nb, 1024, 0, stream>>>(count, N, cur, bsum);
    scan2_kernel<<<1, 64, 0, stream>>>(bsum, nb);
    scatter_kernel<<<(E + 255) / 256, 256, 0, stream>>>(ei, E, flag, tarr, last_up,
                                                        cur, bsum, ed_s);
    wconv_kernel<<<(5 * 16384 + 255) / 256, 256, 0, stream>>>(Wq, Wk, Wv, Wskip, We, Wt, Wet);
    proj_kernel<<<(N + 63) / 64, 256, 0, stream>>>(x, Wt, bq, bk, bv, bskip,
                                                   q_, kbf_, vbf_, out, N);
    edge_kernel<<<(E + 63) / 64, 256, 0, stream>>>(ed_s, msg, time_w, time_b, Wet,
                                                   q_, kbf_, vbf_, num, den_, E);
    norm_kernel<<<(N * 32 + 255) / 256, 256, 0, stream>>>(num, den_, out, N);
}